// Round 13
// baseline (624.596 us; speedup 1.0000x reference)
//
#include <hip/hip_runtime.h>
#include <hip/hip_bf16.h>
#include <math.h>

#define IN_D 128
#define HID_D 128
#define OUT_D 64
#define CAP 64   // bucket capacity per node; Poisson(12) max over 50K nodes << 64

typedef __attribute__((ext_vector_type(8))) short bf16x8;
typedef __attribute__((ext_vector_type(4))) float f32x4;

__device__ __forceinline__ unsigned short f2bf(float f) {
    unsigned u = __float_as_uint(f);
    u += 0x7fffu + ((u >> 16) & 1u);   // RTNE
    return (unsigned short)(u >> 16);
}
__device__ __forceinline__ float bf2f(unsigned short h) {
    return __uint_as_float(((unsigned)h) << 16);
}

// ---- bucket fill (no count/alloc passes) + fused independent weight prep ----
__global__ __launch_bounds__(256) void k_fill_prep(
        const int* __restrict__ src_idx, const int* __restrict__ dst_idx,
        int* __restrict__ cnt, unsigned short* __restrict__ elist, int E,
        const float* __restrict__ W1, const float* __restrict__ F1,
        const float* __restrict__ W2, const float* __restrict__ F2,
        const float* __restrict__ Wp,
        unsigned short* __restrict__ wc1, unsigned short* __restrict__ wc2,
        unsigned short* __restrict__ wpb) {
    int e = blockIdx.x * 256 + threadIdx.x;
    if (e < E) {
        int d = dst_idx[e];
        int pos = atomicAdd(&cnt[d], 1);
        elist[(size_t)d * CAP + pos] = (unsigned short)src_idx[e];
    }
    const int NW = HID_D * IN_D;          // 16384
    const int NC = 3 * NW;                // 49152
    const int NP = OUT_D * HID_D;         // 8192
    int i = e;
    if (i < NC) {
        wc1[i] = f2bf(i < NW ? W1[i] : F1[i - NW]);
    } else if (i < 2 * NC) {
        int j = i - NC;
        wc2[j] = f2bf(j < NW ? W2[j] : F2[j - NW]);
    } else if (i < 2 * NC + NP) {
        int j = i - 2 * NC;
        wpb[j] = f2bf(Wp[j]);
    }
}

// ---- fused GEMM + FiLM, 64 rows/block (round-11 best config) ----
__device__ __forceinline__ bf16x8 load_frag(const unsigned short* p) {
    return *(const bf16x8*)p;
}
__device__ __forceinline__ bf16x8 load_frag(const float* p) {
    float4 u = ((const float4*)p)[0];
    float4 w = ((const float4*)p)[1];
    bf16x8 r;
    r[0] = (short)f2bf(u.x); r[1] = (short)f2bf(u.y);
    r[2] = (short)f2bf(u.z); r[3] = (short)f2bf(u.w);
    r[4] = (short)f2bf(w.x); r[5] = (short)f2bf(w.y);
    r[6] = (short)f2bf(w.z); r[7] = (short)f2bf(w.w);
    return r;
}

// rep/zmask: diagnostic repeat (zmask==0 at runtime; off chain defeats CSE/hoist).
template <typename XT>
__global__ __launch_bounds__(256, 2) void k_msg(const XT* __restrict__ X,
                                                const unsigned short* __restrict__ Wc,
                                                unsigned short* __restrict__ Msg, int n,
                                                int rep, int zmask) {
    const int row0 = blockIdx.x << 6;
    const int wave = threadIdx.x >> 6;
    const int lane = threadIdx.x & 63;
    const int lr = lane & 15;
    const int quad = lane >> 4;

    int off = 0;
    for (int rp = 0; rp < rep; rp++) {
        bf16x8 a[4][4];   // [rowtile][kstep]
        #pragma unroll
        for (int rt = 0; rt < 4; rt++) {
            int r = row0 + rt * 16 + lr;
            if (r > n - 1) r = n - 1;
            const XT* xp = X + (size_t)r * IN_D + quad * 8 + off;
            #pragma unroll
            for (int s = 0; s < 4; s++) a[rt][s] = load_frag(xp + 32 * s);
        }

        const int t0 = wave * 2;
        const int tidx[6] = {t0, t0 + 1, t0 + 8, t0 + 9, t0 + 16, t0 + 17};
        f32x4 acc[6][4];
        #pragma unroll
        for (int u = 0; u < 6; u++)
            #pragma unroll
            for (int rt = 0; rt < 4; rt++) acc[u][rt] = (f32x4){0.f, 0.f, 0.f, 0.f};

        #pragma unroll
        for (int s = 0; s < 4; s++) {
            #pragma unroll
            for (int u = 0; u < 6; u++) {
                const bf16x8 b = *(const bf16x8*)(Wc + (size_t)(16 * tidx[u] + lr) * IN_D + quad * 8 + 32 * s + off);
                #pragma unroll
                for (int rt = 0; rt < 4; rt++)
                    acc[u][rt] = __builtin_amdgcn_mfma_f32_16x16x32_bf16(a[rt][s], b, acc[u][rt], 0, 0, 0);
            }
        }
        #pragma unroll
        for (int u = 0; u < 2; u++) {
            #pragma unroll
            for (int rt = 0; rt < 4; rt++) {
                #pragma unroll
                for (int r = 0; r < 4; r++) {
                    int row = row0 + rt * 16 + quad * 4 + r;
                    if (row < n) {
                        float v = acc[2 + u][rt][r] * acc[u][rt][r] + acc[4 + u][rt][r];
                        v = v > 0.f ? v : 0.f;
                        Msg[(size_t)row * HID_D + 16 * (t0 + u) + lr] = f2bf(v);
                    }
                }
            }
        }
        off += zmask & (int)__float_as_uint(acc[0][0][0]);
    }
}

// ---- bucket aggregate + fused LayerNorm (round-11 shfl-preload loop) ----
__global__ __launch_bounds__(256) void k_agg_ln(const unsigned short* __restrict__ Msg,
                                                const unsigned short* __restrict__ elist,
                                                const int* __restrict__ cnt,
                                                const float* __restrict__ gamma,
                                                const float* __restrict__ beta,
                                                unsigned short* __restrict__ Hout, int n,
                                                int rep, int zmask) {
    int node = blockIdx.x * 4 + (threadIdx.x >> 6);
    int lane = threadIdx.x & 63;
    int half = lane >> 5;
    int l = lane & 31;
    if (node >= n) return;
    const unsigned short* seg = elist + (size_t)node * CAP;
    int deg = cnt[node];

    int off = 0;
    for (int rp = 0; rp < rep; rp++) {
        int myidx = seg[lane + off];   // one coalesced 128B load per wave
        float a0 = 0.f, a1 = 0.f, a2 = 0.f, a3 = 0.f;

#define ACC4(v) { a0 += bf2f((unsigned short)((v).x & 0xffffu)); \
                  a1 += bf2f((unsigned short)((v).x >> 16));     \
                  a2 += bf2f((unsigned short)((v).y & 0xffffu)); \
                  a3 += bf2f((unsigned short)((v).y >> 16)); }

        int i = 0;
        for (; i + 4 <= deg; i += 4) {
            int iA = __shfl(myidx, i + half);
            int iB = __shfl(myidx, i + 2 + half);
            uint2 vA = *(const uint2*)(Msg + (size_t)iA * HID_D + l * 4);
            uint2 vB = *(const uint2*)(Msg + (size_t)iB * HID_D + l * 4);
            ACC4(vA);
            ACC4(vB);
        }
        for (; i + 2 <= deg; i += 2) {
            int iA = __shfl(myidx, i + half);
            uint2 vA = *(const uint2*)(Msg + (size_t)iA * HID_D + l * 4);
            ACC4(vA);
        }
        if (i < deg && half == 0) {
            int iA = __shfl(myidx, i);
            uint2 vA = *(const uint2*)(Msg + (size_t)iA * HID_D + l * 4);
            ACC4(vA);
        }
#undef ACC4

        a0 += __shfl_xor(a0, 32);
        a1 += __shfl_xor(a1, 32);
        a2 += __shfl_xor(a2, 32);
        a3 += __shfl_xor(a3, 32);

        float s = a0 + a1 + a2 + a3;
        float sq = a0 * a0 + a1 * a1 + a2 * a2 + a3 * a3;
        #pragma unroll
        for (int d = 16; d; d >>= 1) {
            s += __shfl_xor(s, d);
            sq += __shfl_xor(sq, d);
        }
        float mu = s * (1.f / 128.f);
        float var = sq * (1.f / 128.f) - mu * mu;
        float rs = rsqrtf(var + 1e-5f);
        float4 g4 = ((const float4*)gamma)[l];
        float4 b4 = ((const float4*)beta)[l];
        float y0 = (a0 - mu) * rs * g4.x + b4.x;
        float y1 = (a1 - mu) * rs * g4.y + b4.y;
        float y2 = (a2 - mu) * rs * g4.z + b4.z;
        float y3 = (a3 - mu) * rs * g4.w + b4.w;
        if (half == 0) {
            uint2 o;
            o.x = (unsigned)f2bf(y0) | ((unsigned)f2bf(y1) << 16);
            o.y = (unsigned)f2bf(y2) | ((unsigned)f2bf(y3) << 16);
            *(uint2*)(Hout + (size_t)node * HID_D + l * 4) = o;
        }
        off += zmask & (int)__float_as_uint(y0);
    }
}

// ---- projection: out = sigmoid(h @ Wp^T + bp), 64 rows/block ----
__global__ __launch_bounds__(256) void k_proj(const unsigned short* __restrict__ H,
                                              const unsigned short* __restrict__ Wpb,
                                              const float* __restrict__ bp,
                                              float* __restrict__ out, int n,
                                              int rep, int zmask) {
    const int row0 = blockIdx.x << 6;
    const int wave = threadIdx.x >> 6;
    const int lane = threadIdx.x & 63;
    const int lr = lane & 15;
    const int quad = lane >> 4;

    int off = 0;
    for (int rp = 0; rp < rep; rp++) {
        f32x4 acc[4];
        #pragma unroll
        for (int rt = 0; rt < 4; rt++) acc[rt] = (f32x4){0.f, 0.f, 0.f, 0.f};

        #pragma unroll
        for (int s = 0; s < 4; s++) {
            bf16x8 bv = *(const bf16x8*)(Wpb + (size_t)(16 * wave + lr) * HID_D + quad * 8 + 32 * s + off);
            #pragma unroll
            for (int rt = 0; rt < 4; rt++) {
                int r = row0 + rt * 16 + lr;
                if (r > n - 1) r = n - 1;
                bf16x8 av = *(const bf16x8*)(H + (size_t)r * HID_D + quad * 8 + 32 * s + off);
                acc[rt] = __builtin_amdgcn_mfma_f32_16x16x32_bf16(av, bv, acc[rt], 0, 0, 0);
            }
        }
        float bias = bp[16 * wave + lr];
        #pragma unroll
        for (int rt = 0; rt < 4; rt++) {
            #pragma unroll
            for (int r = 0; r < 4; r++) {
                int row = row0 + rt * 16 + quad * 4 + r;
                if (row < n) {
                    float z = acc[rt][r] + bias;
                    out[(size_t)row * OUT_D + 16 * wave + lr] = 1.f / (1.f + __expf(-z));
                }
            }
        }
        off += zmask & (int)__float_as_uint(acc[0][0]);
    }
}

extern "C" void kernel_launch(void* const* d_in, const int* in_sizes, int n_in,
                              void* d_out, int out_size, void* d_ws, size_t ws_size,
                              hipStream_t stream) {
    const float* features = (const float*)d_in[0];
    const int* src = (const int*)d_in[1];
    const int* dst = (const int*)d_in[2];
    const float* W1 = (const float*)d_in[3];
    const float* F1 = (const float*)d_in[4];
    const float* g1 = (const float*)d_in[5];
    const float* b1 = (const float*)d_in[6];
    const float* W2 = (const float*)d_in[7];
    const float* F2 = (const float*)d_in[8];
    const float* g2 = (const float*)d_in[9];
    const float* b2 = (const float*)d_in[10];
    const float* Wp = (const float*)d_in[11];
    const float* bp = (const float*)d_in[12];

    const int N = in_sizes[0] / IN_D;   // 50000
    const int E = in_sizes[1];          // 600000
    float* out = (float*)d_out;

    char* p = (char*)d_ws;
    auto alloc = [&](size_t b) -> char* {
        char* r = p;
        p += (b + 255) & ~(size_t)255;
        return r;
    };
    unsigned short* buf0 = (unsigned short*)alloc((size_t)N * HID_D * 2);
    unsigned short* buf1 = (unsigned short*)alloc((size_t)N * HID_D * 2);
    unsigned short* wc1  = (unsigned short*)alloc((size_t)3 * HID_D * IN_D * 2);
    unsigned short* wc2  = (unsigned short*)alloc((size_t)3 * HID_D * HID_D * 2);
    unsigned short* wpb  = (unsigned short*)alloc((size_t)OUT_D * HID_D * 2);
    int* cnt    = (int*)alloc((size_t)N * 4);
    unsigned short* elist = (unsigned short*)alloc((size_t)N * CAP * 2);  // 6.4 MB

    const int eb = (E + 255) / 256;       // 2344
    const int mb = (N + 63) / 64;         // 782
    const int ab = (N + 3) / 4;           // 12500

    const int REP = 5;                    // diagnostic repeat (idempotent kernels)
    const int ZM = 0;                     // runtime-zero mask feeding the dep chain

    hipMemsetAsync(cnt, 0, (size_t)N * 4, stream);
    k_fill_prep<<<eb, 256, 0, stream>>>(src, dst, cnt, elist, E,
                                        W1, F1, W2, F2, Wp, wc1, wc2, wpb);

    // layer 1
    k_msg<float><<<mb, 256, 0, stream>>>(features, wc1, buf1, N, REP, ZM);
    k_agg_ln<<<ab, 256, 0, stream>>>(buf1, elist, cnt, g1, b1, buf0, N, REP, ZM);
    // layer 2
    k_msg<unsigned short><<<mb, 256, 0, stream>>>(buf0, wc2, buf1, N, REP, ZM);
    k_agg_ln<<<ab, 256, 0, stream>>>(buf1, elist, cnt, g2, b2, buf0, N, REP, ZM);
    // projection + sigmoid
    k_proj<<<mb, 256, 0, stream>>>(buf0, wpb, bp, out, N, REP, ZM);
}

// Round 14
// 236.693 us; speedup vs baseline: 2.6388x; 2.6388x over previous
//
#include <hip/hip_runtime.h>
#include <hip/hip_bf16.h>
#include <math.h>

#define IN_D 128
#define HID_D 128
#define OUT_D 64
#define CAP 64   // bucket capacity per node; Poisson(12) max over 50K nodes << 64

typedef __attribute__((ext_vector_type(8))) short bf16x8;
typedef __attribute__((ext_vector_type(4))) float f32x4;

__device__ __forceinline__ unsigned short f2bf(float f) {
    unsigned u = __float_as_uint(f);
    u += 0x7fffu + ((u >> 16) & 1u);   // RTNE
    return (unsigned short)(u >> 16);
}
__device__ __forceinline__ float bf2f(unsigned short h) {
    return __uint_as_float(((unsigned)h) << 16);
}

// ---- bucket fill (no count/alloc passes) + fused independent weight prep ----
__global__ __launch_bounds__(256) void k_fill_prep(
        const int* __restrict__ src_idx, const int* __restrict__ dst_idx,
        int* __restrict__ cnt, unsigned short* __restrict__ elist, int E,
        const float* __restrict__ W1, const float* __restrict__ F1,
        const float* __restrict__ W2, const float* __restrict__ F2,
        const float* __restrict__ Wp,
        unsigned short* __restrict__ wc1, unsigned short* __restrict__ wc2,
        unsigned short* __restrict__ wpb) {
    int e = blockIdx.x * 256 + threadIdx.x;
    if (e < E) {
        int d = dst_idx[e];
        int pos = atomicAdd(&cnt[d], 1);
        elist[(size_t)d * CAP + pos] = (unsigned short)src_idx[e];
    }
    const int NW = HID_D * IN_D;          // 16384
    const int NC = 3 * NW;                // 49152
    const int NP = OUT_D * HID_D;         // 8192
    int i = e;
    if (i < NC) {
        wc1[i] = f2bf(i < NW ? W1[i] : F1[i - NW]);
    } else if (i < 2 * NC) {
        int j = i - NC;
        wc2[j] = f2bf(j < NW ? W2[j] : F2[j - NW]);
    } else if (i < 2 * NC + NP) {
        int j = i - 2 * NC;
        wpb[j] = f2bf(Wp[j]);
    }
}

// ---- fused GEMM + FiLM: B-resident, grid-stride over 32-row chunks ----
__device__ __forceinline__ bf16x8 load_frag(const unsigned short* p) {
    return *(const bf16x8*)p;
}
__device__ __forceinline__ bf16x8 load_frag(const float* p) {
    float4 u = ((const float4*)p)[0];
    float4 w = ((const float4*)p)[1];
    bf16x8 r;
    r[0] = (short)f2bf(u.x); r[1] = (short)f2bf(u.y);
    r[2] = (short)f2bf(u.z); r[3] = (short)f2bf(u.w);
    r[4] = (short)f2bf(w.x); r[5] = (short)f2bf(w.y);
    r[6] = (short)f2bf(w.z); r[7] = (short)f2bf(w.w);
    return r;
}

// Wc = [W(128); Fgamma(128); Fbeta(128)] x 128 bf16 row-major.
// Block: 4 waves. Wave w owns m col-tiles {2w,2w+1} (+ matching gamma/beta tiles).
// Weights loaded into registers ONCE per block (96 VGPR), then reused across
// all row-chunks this block processes — removes the per-tile B refetch that
// made the old k_msg L2-latency-bound (m13 diag: MfmaUtil 6%, occ 16%).
template <typename XT>
__global__ __launch_bounds__(256, 2) void k_msg(const XT* __restrict__ X,
                                                const unsigned short* __restrict__ Wc,
                                                unsigned short* __restrict__ Msg,
                                                int n, int nchunks) {
    const int wave = threadIdx.x >> 6;
    const int lane = threadIdx.x & 63;
    const int lr = lane & 15;
    const int quad = lane >> 4;
    const int t0 = wave * 2;
    const int tidx[6] = {t0, t0 + 1, t0 + 8, t0 + 9, t0 + 16, t0 + 17};

    // B fragments: 24 x 16B per lane, loaded once
    bf16x8 b[6][4];
    #pragma unroll
    for (int u = 0; u < 6; u++)
        #pragma unroll
        for (int s = 0; s < 4; s++)
            b[u][s] = *(const bf16x8*)(Wc + (size_t)(16 * tidx[u] + lr) * IN_D + quad * 8 + 32 * s);

    for (int c = blockIdx.x; c < nchunks; c += gridDim.x) {
        const int row0 = c << 5;   // 32 rows per chunk

        bf16x8 a[2][4];
        #pragma unroll
        for (int rt = 0; rt < 2; rt++) {
            int r = row0 + rt * 16 + lr;
            if (r > n - 1) r = n - 1;
            const XT* xp = X + (size_t)r * IN_D + quad * 8;
            #pragma unroll
            for (int s = 0; s < 4; s++) a[rt][s] = load_frag(xp + 32 * s);
        }

        f32x4 acc[6][2];
        #pragma unroll
        for (int u = 0; u < 6; u++)
            #pragma unroll
            for (int rt = 0; rt < 2; rt++) acc[u][rt] = (f32x4){0.f, 0.f, 0.f, 0.f};

        #pragma unroll
        for (int s = 0; s < 4; s++)
            #pragma unroll
            for (int u = 0; u < 6; u++)
                #pragma unroll
                for (int rt = 0; rt < 2; rt++)
                    acc[u][rt] = __builtin_amdgcn_mfma_f32_16x16x32_bf16(a[rt][s], b[u][s], acc[u][rt], 0, 0, 0);

        // FiLM: m=acc[0..1], gamma=acc[2..3], beta=acc[4..5]; identical slots.
        #pragma unroll
        for (int u = 0; u < 2; u++) {
            #pragma unroll
            for (int rt = 0; rt < 2; rt++) {
                #pragma unroll
                for (int r = 0; r < 4; r++) {
                    int row = row0 + rt * 16 + quad * 4 + r;
                    if (row < n) {
                        float v = acc[2 + u][rt][r] * acc[u][rt][r] + acc[4 + u][rt][r];
                        v = v > 0.f ? v : 0.f;
                        Msg[(size_t)row * HID_D + 16 * (t0 + u) + lr] = f2bf(v);
                    }
                }
            }
        }
    }
}

// ---- bucket aggregate + fused LayerNorm (round-11 shfl-preload loop) ----
__global__ __launch_bounds__(256) void k_agg_ln(const unsigned short* __restrict__ Msg,
                                                const unsigned short* __restrict__ elist,
                                                const int* __restrict__ cnt,
                                                const float* __restrict__ gamma,
                                                const float* __restrict__ beta,
                                                unsigned short* __restrict__ Hout, int n) {
    int node = blockIdx.x * 4 + (threadIdx.x >> 6);
    int lane = threadIdx.x & 63;
    int half = lane >> 5;
    int l = lane & 31;
    if (node >= n) return;
    const unsigned short* seg = elist + (size_t)node * CAP;
    int deg = cnt[node];
    int myidx = seg[lane];            // one coalesced 128B load per wave
    float a0 = 0.f, a1 = 0.f, a2 = 0.f, a3 = 0.f;

#define ACC4(v) { a0 += bf2f((unsigned short)((v).x & 0xffffu)); \
                  a1 += bf2f((unsigned short)((v).x >> 16));     \
                  a2 += bf2f((unsigned short)((v).y & 0xffffu)); \
                  a3 += bf2f((unsigned short)((v).y >> 16)); }

    int i = 0;
    for (; i + 4 <= deg; i += 4) {
        int iA = __shfl(myidx, i + half);
        int iB = __shfl(myidx, i + 2 + half);
        uint2 vA = *(const uint2*)(Msg + (size_t)iA * HID_D + l * 4);
        uint2 vB = *(const uint2*)(Msg + (size_t)iB * HID_D + l * 4);
        ACC4(vA);
        ACC4(vB);
    }
    for (; i + 2 <= deg; i += 2) {
        int iA = __shfl(myidx, i + half);
        uint2 vA = *(const uint2*)(Msg + (size_t)iA * HID_D + l * 4);
        ACC4(vA);
    }
    if (i < deg && half == 0) {
        int iA = __shfl(myidx, i);
        uint2 vA = *(const uint2*)(Msg + (size_t)iA * HID_D + l * 4);
        ACC4(vA);
    }
#undef ACC4

    a0 += __shfl_xor(a0, 32);
    a1 += __shfl_xor(a1, 32);
    a2 += __shfl_xor(a2, 32);
    a3 += __shfl_xor(a3, 32);

    float s = a0 + a1 + a2 + a3;
    float sq = a0 * a0 + a1 * a1 + a2 * a2 + a3 * a3;
    #pragma unroll
    for (int d = 16; d; d >>= 1) {
        s += __shfl_xor(s, d);
        sq += __shfl_xor(sq, d);
    }
    float mu = s * (1.f / 128.f);
    float var = sq * (1.f / 128.f) - mu * mu;
    float rs = rsqrtf(var + 1e-5f);
    float4 g4 = ((const float4*)gamma)[l];
    float4 b4 = ((const float4*)beta)[l];
    float y0 = (a0 - mu) * rs * g4.x + b4.x;
    float y1 = (a1 - mu) * rs * g4.y + b4.y;
    float y2 = (a2 - mu) * rs * g4.z + b4.z;
    float y3 = (a3 - mu) * rs * g4.w + b4.w;
    if (half == 0) {
        uint2 o;
        o.x = (unsigned)f2bf(y0) | ((unsigned)f2bf(y1) << 16);
        o.y = (unsigned)f2bf(y2) | ((unsigned)f2bf(y3) << 16);
        *(uint2*)(Hout + (size_t)node * HID_D + l * 4) = o;
    }
}

// ---- projection: out = sigmoid(h @ Wp^T + bp), 64 rows/block ----
__global__ __launch_bounds__(256) void k_proj(const unsigned short* __restrict__ H,
                                              const unsigned short* __restrict__ Wpb,
                                              const float* __restrict__ bp,
                                              float* __restrict__ out, int n) {
    const int row0 = blockIdx.x << 6;
    const int wave = threadIdx.x >> 6;
    const int lane = threadIdx.x & 63;
    const int lr = lane & 15;
    const int quad = lane >> 4;

    f32x4 acc[4];
    #pragma unroll
    for (int rt = 0; rt < 4; rt++) acc[rt] = (f32x4){0.f, 0.f, 0.f, 0.f};

    #pragma unroll
    for (int s = 0; s < 4; s++) {
        bf16x8 bv = *(const bf16x8*)(Wpb + (size_t)(16 * wave + lr) * HID_D + quad * 8 + 32 * s);
        #pragma unroll
        for (int rt = 0; rt < 4; rt++) {
            int r = row0 + rt * 16 + lr;
            if (r > n - 1) r = n - 1;
            bf16x8 av = *(const bf16x8*)(H + (size_t)r * HID_D + quad * 8 + 32 * s);
            acc[rt] = __builtin_amdgcn_mfma_f32_16x16x32_bf16(av, bv, acc[rt], 0, 0, 0);
        }
    }
    float bias = bp[16 * wave + lr];
    #pragma unroll
    for (int rt = 0; rt < 4; rt++) {
        #pragma unroll
        for (int r = 0; r < 4; r++) {
            int row = row0 + rt * 16 + quad * 4 + r;
            if (row < n) {
                float z = acc[rt][r] + bias;
                out[(size_t)row * OUT_D + 16 * wave + lr] = 1.f / (1.f + __expf(-z));
            }
        }
    }
}

extern "C" void kernel_launch(void* const* d_in, const int* in_sizes, int n_in,
                              void* d_out, int out_size, void* d_ws, size_t ws_size,
                              hipStream_t stream) {
    const float* features = (const float*)d_in[0];
    const int* src = (const int*)d_in[1];
    const int* dst = (const int*)d_in[2];
    const float* W1 = (const float*)d_in[3];
    const float* F1 = (const float*)d_in[4];
    const float* g1 = (const float*)d_in[5];
    const float* b1 = (const float*)d_in[6];
    const float* W2 = (const float*)d_in[7];
    const float* F2 = (const float*)d_in[8];
    const float* g2 = (const float*)d_in[9];
    const float* b2 = (const float*)d_in[10];
    const float* Wp = (const float*)d_in[11];
    const float* bp = (const float*)d_in[12];

    const int N = in_sizes[0] / IN_D;   // 50000
    const int E = in_sizes[1];          // 600000
    float* out = (float*)d_out;

    char* p = (char*)d_ws;
    auto alloc = [&](size_t b) -> char* {
        char* r = p;
        p += (b + 255) & ~(size_t)255;
        return r;
    };
    unsigned short* buf0 = (unsigned short*)alloc((size_t)N * HID_D * 2);
    unsigned short* buf1 = (unsigned short*)alloc((size_t)N * HID_D * 2);
    unsigned short* wc1  = (unsigned short*)alloc((size_t)3 * HID_D * IN_D * 2);
    unsigned short* wc2  = (unsigned short*)alloc((size_t)3 * HID_D * HID_D * 2);
    unsigned short* wpb  = (unsigned short*)alloc((size_t)OUT_D * HID_D * 2);
    int* cnt    = (int*)alloc((size_t)N * 4);
    unsigned short* elist = (unsigned short*)alloc((size_t)N * CAP * 2);  // 6.4 MB

    const int eb = (E + 255) / 256;       // 2344
    const int mc = (N + 31) / 32;         // 1563 chunks (32 rows)
    const int mg = 512;                   // 2 blocks/CU, grid-stride over chunks
    const int pb = (N + 63) / 64;         // 782
    const int ab = (N + 3) / 4;           // 12500

    // bucket-CSR: memset counters -> fill(+weight prep). No count/alloc passes.
    hipMemsetAsync(cnt, 0, (size_t)N * 4, stream);
    k_fill_prep<<<eb, 256, 0, stream>>>(src, dst, cnt, elist, E,
                                        W1, F1, W2, F2, Wp, wc1, wc2, wpb);

    // layer 1 (reads fp32 features directly)
    k_msg<float><<<mg, 256, 0, stream>>>(features, wc1, buf1, N, mc);
    k_agg_ln<<<ab, 256, 0, stream>>>(buf1, elist, cnt, g1, b1, buf0, N);
    // layer 2
    k_msg<unsigned short><<<mg, 256, 0, stream>>>(buf0, wc2, buf1, N, mc);
    k_agg_ln<<<ab, 256, 0, stream>>>(buf1, elist, cnt, g2, b2, buf0, N);
    // projection + sigmoid
    k_proj<<<pb, 256, 0, stream>>>(buf0, wpb, bp, out, N);
}